// Round 1
// baseline (603.190 us; speedup 1.0000x reference)
//
#include <hip/hip_runtime.h>

#define B_ 1024
#define T_ 128
#define H_ENC_ 1024
#define L_ 2
#define H_PRED_ 320
#define MAXLEN_ 256
#define BLANK_ 28
#define MAX_SYMBOLS_ 30

// Output offsets (in float elements), concatenated in reference return order.
#define O_SA     0
#define O_RES    (O_SA + B_)
#define O_RIDX   (O_RES + B_*MAXLEN_)
#define O_TIDX   (O_RIDX + B_)
#define O_FI     (O_TIDX + B_)
#define O_PREG   (O_FI + B_*H_ENC_)
#define O_PREHG  (O_PREG + B_)
#define O_PRECG  (O_PREHG + L_*B_*H_PRED_)
#define O_DONE   (O_PRECG + L_*B_*H_PRED_)

__global__ __launch_bounds__(256) void decoder_update(
    const int*   __restrict__ symbols,
    const int*   __restrict__ symbols_added,
    const int*   __restrict__ res,
    const int*   __restrict__ res_idx,
    const float* __restrict__ f,
    const int*   __restrict__ f_lens,
    const int*   __restrict__ time_idx,
    const float* __restrict__ fi,
    const int*   __restrict__ pre_g,
    const float* __restrict__ pre_hg,
    const float* __restrict__ pre_cg,
    const float* __restrict__ hg,
    const float* __restrict__ cg,
    float*       __restrict__ out)
{
    const int b = blockIdx.x;   // one block per batch row
    const int t = threadIdx.x;  // 256 threads

    // Per-row scalars (redundant per thread; served from L1/L2)
    const int sym = symbols[b];
    const int sa  = symbols_added[b];
    const int ti  = time_idx[b];
    const int fl  = f_lens[b];
    const int ri  = res_idx[b];
    const bool nb = (sym != BLANK_) && (sa < MAX_SYMBOLS_) && (ti < fl);
    const int ti_new = nb ? ti : ti + 1;
    int tg = ti_new;
    if (tg < 0) tg = 0;
    if (tg > T_ - 1) tg = T_ - 1;

    // ---- res row: 256 ints, 1 per thread, write as float ----
    {
        const int rv = res[b * MAXLEN_ + t];
        const float ov = (nb && t == ri) ? (float)sym : (float)rv;
        out[O_RES + b * MAXLEN_ + t] = ov;
    }

    // ---- fi row: 1024 floats = 256 float4, 1 per thread ----
    {
        const float4* src = nb
            ? (const float4*)(fi + (size_t)b * H_ENC_)
            : (const float4*)(f + ((size_t)b * T_ + tg) * H_ENC_);
        float4* dst = (float4*)(out + O_FI + (size_t)b * H_ENC_);
        dst[t] = src[t];
    }

    // ---- pre_hg / pre_cg select: 2 tensors x L_ x 320 floats = 320 float4 ----
    {
        const float4* hsrc = (const float4*)(nb ? hg : pre_hg);
        const float4* csrc = (const float4*)(nb ? cg : pre_cg);
        float4* hdst = (float4*)(out + O_PREHG);
        float4* cdst = (float4*)(out + O_PRECG);
        const int V = H_PRED_ / 4;  // 80 float4 per (l,b) row
        for (int i = t; i < 2 * L_ * V; i += 256) {
            const int which = (i < L_ * V) ? 0 : 1;
            const int idx   = (i < L_ * V) ? i : i - L_ * V;
            const int l = idx / V;
            const int k = idx - l * V;
            const size_t off = ((size_t)l * B_ + b) * V + k;
            if (which == 0) hdst[off] = hsrc[off];
            else            cdst[off] = csrc[off];
        }
    }

    // ---- block 0: small per-b outputs + done all-reduce ----
    if (b == 0) {
        __shared__ int alldone;
        if (t == 0) alldone = 1;
        __syncthreads();
        for (int bb = t; bb < B_; bb += 256) {
            const int s2  = symbols[bb];
            const int sa2 = symbols_added[bb];
            const int ti2 = time_idx[bb];
            const int fl2 = f_lens[bb];
            const int ri2 = res_idx[bb];
            const int pg2 = pre_g[bb];
            const bool nb2 = (s2 != BLANK_) && (sa2 < MAX_SYMBOLS_) && (ti2 < fl2);
            const int tin2 = nb2 ? ti2 : ti2 + 1;
            out[O_SA   + bb] = (float)(nb2 ? sa2 + 1 : 0);
            out[O_RIDX + bb] = (float)(ri2 + (nb2 ? 1 : 0));
            out[O_TIDX + bb] = (float)tin2;
            out[O_PREG + bb] = (float)(nb2 ? s2 : pg2);
            if (tin2 < fl2) alldone = 0;  // benign race: all writers store 0
        }
        __syncthreads();
        if (t == 0) out[O_DONE] = (float)alldone;
    }
}

extern "C" void kernel_launch(void* const* d_in, const int* in_sizes, int n_in,
                              void* d_out, int out_size, void* d_ws, size_t ws_size,
                              hipStream_t stream) {
    (void)in_sizes; (void)n_in; (void)out_size; (void)d_ws; (void)ws_size;
    decoder_update<<<dim3(B_), dim3(256), 0, stream>>>(
        (const int*)  d_in[0],   // symbols
        (const int*)  d_in[1],   // symbols_added
        (const int*)  d_in[2],   // res
        (const int*)  d_in[3],   // res_idx
        (const float*)d_in[4],   // f
        (const int*)  d_in[5],   // f_lens
        (const int*)  d_in[6],   // time_idx
        (const float*)d_in[7],   // fi
        (const int*)  d_in[8],   // pre_g
        (const float*)d_in[9],   // pre_hg
        (const float*)d_in[10],  // pre_cg
        (const float*)d_in[11],  // hg
        (const float*)d_in[12],  // cg
        (float*)      d_out);
}